// Round 1
// baseline (30263.086 us; speedup 1.0000x reference)
//
#include <hip/hip_runtime.h>
#include <math.h>

#define B_SZ 32
#define T_SZ 2048
#define DIN 256
#define DH 256
#define FOUR_D 1024

__device__ __forceinline__ float fsig(float x) {
    return 1.0f / (1.0f + __expf(-x));
}
__device__ __forceinline__ float ftanh(float x) {
    // tanh(x) = 2*sigmoid(2x) - 1; saturates correctly for large |x|
    float e = __expf(-2.0f * x);
    return 2.0f / (1.0f + e) - 1.0f;
}

__global__ void zero_kernel(float* p, int n) {
    int i = blockIdx.x * blockDim.x + threadIdx.x;
    if (i < n) p[i] = 0.0f;
}

// px[r][f] = bias[f] + sum_k x_row(r)[k] * W[k][f]
// r (chunk-local) = tt*32 + b ; global t = t0 + tt
// block: 256 threads, 16 rows x 1024 cols (4 cols/thread)
__global__ __launch_bounds__(256) void px_gemm(
    const float* __restrict__ x, const float* __restrict__ W,
    const float* __restrict__ bias, float* __restrict__ px,
    int t0)
{
    __shared__ float xt[16][DIN];
    const int tid = threadIdx.x;
    const int rbase = blockIdx.x * 16;

    // stage 16 rows of x (full K=256) into LDS: each thread 16 consecutive floats
    {
        int row = tid >> 4;            // 0..15
        int seg = (tid & 15) * 16;     // 0..240
        int r = rbase + row;
        int bb = r & 31;
        int tt = r >> 5;
        const float4* s4 = (const float4*)(x + ((size_t)bb * T_SZ + (size_t)(t0 + tt)) * DIN + seg);
        float4* dst = (float4*)&xt[row][seg];
        dst[0] = s4[0]; dst[1] = s4[1]; dst[2] = s4[2]; dst[3] = s4[3];
    }
    __syncthreads();

    const int j = tid * 4;  // column base 0..1020
    float4 bv = *(const float4*)&bias[j];
    float acc[16][4];
#pragma unroll
    for (int r = 0; r < 16; ++r) {
        acc[r][0] = bv.x; acc[r][1] = bv.y; acc[r][2] = bv.z; acc[r][3] = bv.w;
    }

    for (int k = 0; k < DIN; k += 4) {
        float4 w0 = *(const float4*)&W[(size_t)(k + 0) * FOUR_D + j];
        float4 w1 = *(const float4*)&W[(size_t)(k + 1) * FOUR_D + j];
        float4 w2 = *(const float4*)&W[(size_t)(k + 2) * FOUR_D + j];
        float4 w3 = *(const float4*)&W[(size_t)(k + 3) * FOUR_D + j];
#pragma unroll
        for (int r = 0; r < 16; ++r) {
            float4 xv = *(const float4*)&xt[r][k];
            acc[r][0] += xv.x * w0.x + xv.y * w1.x + xv.z * w2.x + xv.w * w3.x;
            acc[r][1] += xv.x * w0.y + xv.y * w1.y + xv.z * w2.y + xv.w * w3.y;
            acc[r][2] += xv.x * w0.z + xv.y * w1.z + xv.z * w2.z + xv.w * w3.z;
            acc[r][3] += xv.x * w0.w + xv.y * w1.w + xv.z * w2.w + xv.w * w3.w;
        }
    }

#pragma unroll
    for (int r = 0; r < 16; ++r) {
        float4 st = make_float4(acc[r][0], acc[r][1], acc[r][2], acc[r][3]);
        *(float4*)&px[((size_t)(rbase + r)) * FOUR_D + j] = st;
    }
}

// Persistent per-batch scan over ct timesteps.
// block b = batch index; 512 threads, 2 preact columns each.
__global__ __launch_bounds__(512) void lstm_scan(
    const float* __restrict__ px, const float* __restrict__ U,
    float* __restrict__ out, float* __restrict__ hstate, float* __restrict__ cstate,
    int t0, int ct)
{
    __shared__ float h_lds[DH];
    __shared__ float pre_lds[FOUR_D];
    const int b = blockIdx.x;
    const int tid = threadIdx.x;

    float c_reg = 0.0f;
    if (tid < DH) {
        c_reg = cstate[b * DH + tid];
        h_lds[tid] = hstate[b * DH + tid];
    }
    __syncthreads();

    const float* Ubase = U + tid * 2;

    for (int tt = 0; tt < ct; ++tt) {
        const float* pxr = px + ((size_t)tt * B_SZ + b) * FOUR_D + tid * 2;
        float2 p2 = *(const float2*)pxr;
        float a0 = p2.x, a1 = p2.y;

#pragma unroll 4
        for (int k = 0; k < DH; k += 4) {
            float4 h4 = *(const float4*)&h_lds[k];
            float2 u0 = *(const float2*)&Ubase[(size_t)(k + 0) * FOUR_D];
            float2 u1 = *(const float2*)&Ubase[(size_t)(k + 1) * FOUR_D];
            float2 u2 = *(const float2*)&Ubase[(size_t)(k + 2) * FOUR_D];
            float2 u3 = *(const float2*)&Ubase[(size_t)(k + 3) * FOUR_D];
            a0 += h4.x * u0.x + h4.y * u1.x + h4.z * u2.x + h4.w * u3.x;
            a1 += h4.x * u0.y + h4.y * u1.y + h4.z * u2.y + h4.w * u3.y;
        }

        *(float2*)&pre_lds[tid * 2] = make_float2(a0, a1);
        __syncthreads();

        if (tid < DH) {
            float pi = pre_lds[tid];
            float pf = pre_lds[DH + tid];
            float po = pre_lds[2 * DH + tid];
            float pg = pre_lds[3 * DH + tid];
            float ig = fsig(pi);
            float fg = fsig(pf);
            float og = fsig(po);
            float gg = ftanh(pg);
            float cn = fg * c_reg + ig * gg;
            c_reg = cn;
            float hn = og * ftanh(cn);
            h_lds[tid] = hn;
            out[((size_t)b * T_SZ + (size_t)(t0 + tt)) * DH + tid] = hn;
        }
        __syncthreads();
    }

    if (tid < DH) {
        cstate[b * DH + tid] = c_reg;
        hstate[b * DH + tid] = h_lds[tid];
    }
}

extern "C" void kernel_launch(void* const* d_in, const int* in_sizes, int n_in,
                              void* d_out, int out_size, void* d_ws, size_t ws_size,
                              hipStream_t stream) {
    const float* x    = (const float*)d_in[0];
    const float* W    = (const float*)d_in[1];
    const float* U    = (const float*)d_in[2];
    const float* bias = (const float*)d_in[3];
    float* out = (float*)d_out;

    // ws layout: hstate[32*256] | cstate[32*256] | (align 256B) | px chunk buffer
    float* hstate = (float*)d_ws;
    float* cstate = hstate + B_SZ * DH;
    size_t state_bytes = (size_t)2 * B_SZ * DH * sizeof(float);
    size_t px_off = (state_bytes + 255) & ~(size_t)255;
    float* pxbuf = (float*)((char*)d_ws + px_off);

    size_t avail = (ws_size > px_off) ? (ws_size - px_off) : 0;
    size_t per_step = (size_t)B_SZ * FOUR_D * sizeof(float);  // 128 KB
    long ct_max = (long)(avail / per_step);
    int CT = (ct_max >= T_SZ) ? T_SZ : (int)ct_max;
    if (CT < 1) CT = 1;  // ws too small: will still launch (harness ws expected >= 128KB)

    // zero h0/c0
    zero_kernel<<<(B_SZ * DH * 2 + 255) / 256, 256, 0, stream>>>(hstate, B_SZ * DH * 2);

    for (int t0 = 0; t0 < T_SZ; t0 += CT) {
        int ct = (T_SZ - t0 < CT) ? (T_SZ - t0) : CT;
        int rows = ct * B_SZ;             // multiple of 32 -> multiple of 16
        px_gemm<<<rows / 16, 256, 0, stream>>>(x, W, bias, pxbuf, t0);
        lstm_scan<<<B_SZ, 512, 0, stream>>>(pxbuf, U, out, hstate, cstate, t0, ct);
    }
}

// Round 2
// 5454.169 us; speedup vs baseline: 5.5486x; 5.5486x over previous
//
#include <hip/hip_runtime.h>
#include <math.h>

#define B_SZ 32
#define T_SZ 2048
#define DIN 256
#define DH 256
#define FOUR_D 1024

// transposed scan decomposition
#define NW 32          // workgroups per batch
#define DPW 8          // hidden dims per WG
#define COLS 32        // preact cols per WG (4 gates x DPW)
#define KSEG 8         // k-segments (256 threads = 32 cols x 8 segs)
#define KLEN 32        // k elements per segment
#define USTRIDE 260    // LDS row stride (260%32==4 -> conflict-free b128)

__global__ void zero_ws(unsigned int* p, int n) {
    int i = blockIdx.x * blockDim.x + threadIdx.x;
    if (i < n) p[i] = 0u;
}

// px[r][f] = bias[f] + sum_k x_row(r)[k] * W[k][f];  r = tt*32 + b
__global__ __launch_bounds__(256) void px_gemm(
    const float* __restrict__ x, const float* __restrict__ W,
    const float* __restrict__ bias, float* __restrict__ px,
    int t0)
{
    __shared__ float xt[16][DIN];
    const int tid = threadIdx.x;
    const int rbase = blockIdx.x * 16;

    {
        int row = tid >> 4;
        int seg = (tid & 15) * 16;
        int r = rbase + row;
        int bb = r & 31;
        int tt = r >> 5;
        const float4* s4 = (const float4*)(x + ((size_t)bb * T_SZ + (size_t)(t0 + tt)) * DIN + seg);
        float4* dst = (float4*)&xt[row][seg];
        dst[0] = s4[0]; dst[1] = s4[1]; dst[2] = s4[2]; dst[3] = s4[3];
    }
    __syncthreads();

    const int j = tid * 4;
    float4 bv = *(const float4*)&bias[j];
    float acc[16][4];
#pragma unroll
    for (int r = 0; r < 16; ++r) {
        acc[r][0] = bv.x; acc[r][1] = bv.y; acc[r][2] = bv.z; acc[r][3] = bv.w;
    }

    for (int k = 0; k < DIN; k += 4) {
        float4 w0 = *(const float4*)&W[(size_t)(k + 0) * FOUR_D + j];
        float4 w1 = *(const float4*)&W[(size_t)(k + 1) * FOUR_D + j];
        float4 w2 = *(const float4*)&W[(size_t)(k + 2) * FOUR_D + j];
        float4 w3 = *(const float4*)&W[(size_t)(k + 3) * FOUR_D + j];
#pragma unroll
        for (int r = 0; r < 16; ++r) {
            float4 xv = *(const float4*)&xt[r][k];
            acc[r][0] += xv.x * w0.x + xv.y * w1.x + xv.z * w2.x + xv.w * w3.x;
            acc[r][1] += xv.x * w0.y + xv.y * w1.y + xv.z * w2.y + xv.w * w3.y;
            acc[r][2] += xv.x * w0.z + xv.y * w1.z + xv.z * w2.z + xv.w * w3.z;
            acc[r][3] += xv.x * w0.w + xv.y * w1.w + xv.z * w2.w + xv.w * w3.w;
        }
    }

#pragma unroll
    for (int r = 0; r < 16; ++r) {
        float4 st = make_float4(acc[r][0], acc[r][1], acc[r][2], acc[r][3]);
        *(float4*)&px[((size_t)(rbase + r)) * FOUR_D + j] = st;
    }
}

// Transposed scan: blockIdx = b*NW + w. WG (b,w) owns dims [8w, 8w+8) of batch b,
// i.e. preact cols {256g + 8w + j}. U slice lives in REGISTERS (32 floats/thread).
// h is exchanged between the 32 WGs of a batch via 64-bit agent-scope atomics
// carrying (step_tag<<32 | float_bits), double-buffered by step parity.
__global__ __launch_bounds__(256, 4) void lstm_scan3(
    const float* __restrict__ px, const float* __restrict__ U,
    float* __restrict__ out, unsigned long long* __restrict__ hbuf,
    float* __restrict__ cstate, int t0, int ct)
{
    __shared__ float usl[COLS][USTRIDE];
    __shared__ float h_lds[DH];
    __shared__ float red[KSEG][COLS + 1];
    __shared__ float pre_s[COLS];

    const int wgid = blockIdx.x;
    const int b = wgid >> 5;        // batch (batch-contiguous: no-deadlock cascade)
    const int w = wgid & 31;        // WG-within-batch
    const int tid = threadIdx.x;
    const int c = tid & 31;         // col within WG
    const int seg = tid >> 5;       // 0..7
    const int kbase = seg << 5;

    // ---- one-time: stage U slice to LDS (coalesced-ish), copy my 32 weights to regs
    for (int r = 0; r < 32; ++r) {
        int lin = (r << 8) + tid;       // 0..8191
        int lc = lin & 31;
        int k  = lin >> 5;              // 0..255
        int gg = lc >> 3, jj = lc & 7;
        usl[lc][k] = U[(size_t)k * FOUR_D + (gg << 8) + (w << 3) + jj];
    }
    __syncthreads();
    float ureg[KLEN];
#pragma unroll
    for (int kk = 0; kk < KLEN; ++kk) ureg[kk] = usl[c][kbase + kk];

    float c_reg = 0.0f;
    if (tid < DPW) c_reg = cstate[b * DH + (w << 3) + tid];

    for (int tt = 0; tt < ct; ++tt) {
        const int s = t0 + tt + 1;      // computing h_s from h_{s-1}

        // px prefetch (independent of h -> issued before the spin)
        float pxv = 0.0f;
        if (tid < COLS) {
            int pg = tid >> 3, pj = tid & 7;
            pxv = px[((size_t)tt * B_SZ + b) * FOUR_D + (pg << 8) + (w << 3) + pj];
        }

        // acquire h_{s-1}: each thread polls exactly its own dim
        if (s == 1) {
            h_lds[tid] = 0.0f;
        } else {
            const unsigned long long want = (unsigned long long)(unsigned)(s - 1);
            unsigned long long* slot = hbuf +
                (((size_t)((s - 1) & 1) * B_SZ + b) * DH + tid);
            unsigned long long v;
            do {
                v = __hip_atomic_load(slot, __ATOMIC_RELAXED, __HIP_MEMORY_SCOPE_AGENT);
            } while ((v >> 32) != want);
            h_lds[tid] = __uint_as_float((unsigned)(v & 0xffffffffu));
        }
        __syncthreads();   // B1: h_lds ready

        // GEMV: 32 fp32 FMAs per thread, U in registers, h from LDS (broadcast)
        float partial = 0.0f;
#pragma unroll
        for (int i = 0; i < KLEN; i += 4) {
            float4 h4 = *(const float4*)&h_lds[kbase + i];
            partial += h4.x * ureg[i]     + h4.y * ureg[i + 1]
                     + h4.z * ureg[i + 2] + h4.w * ureg[i + 3];
        }
        red[seg][c] = partial;
        __syncthreads();   // B2: partials ready

        if (tid < COLS) {
            float pre = pxv;
#pragma unroll
            for (int ss = 0; ss < KSEG; ++ss) pre += red[ss][tid];
            pre_s[tid] = pre;
        }
        __syncthreads();   // B3: preacts ready

        if (tid < DPW) {
            float pi = pre_s[tid];
            float pf = pre_s[8 + tid];
            float po = pre_s[16 + tid];
            float pgv = pre_s[24 + tid];
            float ig = 1.0f / (1.0f + __expf(-pi));
            float fg = 1.0f / (1.0f + __expf(-pf));
            float og = 1.0f / (1.0f + __expf(-po));
            float eg = __expf(-2.0f * pgv);
            float gg = 2.0f / (1.0f + eg) - 1.0f;
            float cn = fg * c_reg + ig * gg;
            c_reg = cn;
            float ec = __expf(-2.0f * cn);
            float th = 2.0f / (1.0f + ec) - 1.0f;
            float hn = og * th;
            int d = (w << 3) + tid;
            out[((size_t)b * T_SZ + (size_t)(s - 1)) * DH + d] = hn;
            unsigned long long pv =
                ((unsigned long long)(unsigned)s << 32) |
                (unsigned long long)__float_as_uint(hn);
            __hip_atomic_store(hbuf + (((size_t)(s & 1) * B_SZ + b) * DH + d),
                               pv, __ATOMIC_RELAXED, __HIP_MEMORY_SCOPE_AGENT);
        }
        // no trailing barrier needed: next-step writers of h_lds/red/pre_s are
        // gated behind B1/B2 of the next iteration.
    }

    if (tid < DPW) cstate[b * DH + (w << 3) + tid] = c_reg;
}

extern "C" void kernel_launch(void* const* d_in, const int* in_sizes, int n_in,
                              void* d_out, int out_size, void* d_ws, size_t ws_size,
                              hipStream_t stream) {
    const float* x    = (const float*)d_in[0];
    const float* W    = (const float*)d_in[1];
    const float* U    = (const float*)d_in[2];
    const float* bias = (const float*)d_in[3];
    float* out = (float*)d_out;

    // ws layout: cstate (32KB) | hbuf (128KB) | pxbuf (chunks)
    float* cstate = (float*)d_ws;
    unsigned long long* hbuf = (unsigned long long*)((char*)d_ws + 32 * 1024);
    size_t px_off = 160 * 1024;
    float* pxbuf = (float*)((char*)d_ws + px_off);

    size_t avail = (ws_size > px_off) ? (ws_size - px_off) : 0;
    size_t per_step = (size_t)B_SZ * FOUR_D * sizeof(float);  // 128 KB
    long ct_max = (long)(avail / per_step);
    int CT = (ct_max >= T_SZ) ? T_SZ : (int)ct_max;
    if (CT < 1) CT = 1;

    // zero cstate + hbuf (tags/state) each launch
    int zero_words = (32 * 1024 + 128 * 1024) / 4;
    zero_ws<<<(zero_words + 255) / 256, 256, 0, stream>>>((unsigned int*)d_ws, zero_words);

    for (int t0 = 0; t0 < T_SZ; t0 += CT) {
        int ct = (T_SZ - t0 < CT) ? (T_SZ - t0) : CT;
        int rows = ct * B_SZ;
        px_gemm<<<rows / 16, 256, 0, stream>>>(x, W, bias, pxbuf, t0);
        lstm_scan3<<<B_SZ * NW, 256, 0, stream>>>(pxbuf, U, out, hbuf, cstate, t0, ct);
    }
}

// Round 4
// 3949.569 us; speedup vs baseline: 7.6624x; 1.3810x over previous
//
#include <hip/hip_runtime.h>
#include <math.h>

#define B_SZ 32
#define T_SZ 2048
#define DIN 256
#define DH 256
#define FOUR_D 1024

// transposed scan decomposition: 8 WGs per batch, 512 threads each
#define NW 8           // workgroups per batch
#define DPW 32         // hidden dims per WG
#define COLS 128       // preact cols per WG (4 gates x DPW)
#define KSEG 4         // k-segments (512 threads = 128 cols x 4 segs)
#define KLEN 64        // k elements per segment

__global__ void zero_ws(unsigned int* p, int n) {
    int i = blockIdx.x * blockDim.x + threadIdx.x;
    if (i < n) p[i] = 0u;
}

// px[r][f] = bias[f] + sum_k x_row(r)[k] * W[k][f];  r = tt*32 + b
__global__ __launch_bounds__(256) void px_gemm(
    const float* __restrict__ x, const float* __restrict__ W,
    const float* __restrict__ bias, float* __restrict__ px,
    int t0)
{
    __shared__ float xt[16][DIN];
    const int tid = threadIdx.x;
    const int rbase = blockIdx.x * 16;

    {
        int row = tid >> 4;
        int seg = (tid & 15) * 16;
        int r = rbase + row;
        int bb = r & 31;
        int tt = r >> 5;
        const float4* s4 = (const float4*)(x + ((size_t)bb * T_SZ + (size_t)(t0 + tt)) * DIN + seg);
        float4* dst = (float4*)&xt[row][seg];
        dst[0] = s4[0]; dst[1] = s4[1]; dst[2] = s4[2]; dst[3] = s4[3];
    }
    __syncthreads();

    const int j = tid * 4;
    float4 bv = *(const float4*)&bias[j];
    float acc[16][4];
#pragma unroll
    for (int r = 0; r < 16; ++r) {
        acc[r][0] = bv.x; acc[r][1] = bv.y; acc[r][2] = bv.z; acc[r][3] = bv.w;
    }

    for (int k = 0; k < DIN; k += 4) {
        float4 w0 = *(const float4*)&W[(size_t)(k + 0) * FOUR_D + j];
        float4 w1 = *(const float4*)&W[(size_t)(k + 1) * FOUR_D + j];
        float4 w2 = *(const float4*)&W[(size_t)(k + 2) * FOUR_D + j];
        float4 w3 = *(const float4*)&W[(size_t)(k + 3) * FOUR_D + j];
#pragma unroll
        for (int r = 0; r < 16; ++r) {
            float4 xv = *(const float4*)&xt[r][k];
            acc[r][0] += xv.x * w0.x + xv.y * w1.x + xv.z * w2.x + xv.w * w3.x;
            acc[r][1] += xv.x * w0.y + xv.y * w1.y + xv.z * w2.y + xv.w * w3.y;
            acc[r][2] += xv.x * w0.z + xv.y * w1.z + xv.z * w2.z + xv.w * w3.z;
            acc[r][3] += xv.x * w0.w + xv.y * w1.w + xv.z * w2.w + xv.w * w3.w;
        }
    }

#pragma unroll
    for (int r = 0; r < 16; ++r) {
        float4 st = make_float4(acc[r][0], acc[r][1], acc[r][2], acc[r][3]);
        *(float4*)&px[((size_t)(rbase + r)) * FOUR_D + j] = st;
    }
}

// Transposed scan: blockIdx = b*NW + w. WG (b,w) owns dims [32w, 32w+32),
// i.e. preact cols {256g + 32w + j, j<32}. U slice in registers (64/thread).
// h exchange between the 8 WGs of a batch: 64-bit agent-scope atomics
// carrying (step_tag<<32 | float_bits), double-buffered by step parity.
// Proven-safe protocol (R2): no placement assumptions, no claiming.
__global__ __launch_bounds__(512, 2) void lstm_scan5(
    const float* __restrict__ px, const float* __restrict__ U,
    float* __restrict__ out, unsigned long long* __restrict__ hbuf,
    float* __restrict__ cstate, int t0, int ct)
{
    __shared__ float h_lds[DH];
    __shared__ float red[KSEG][COLS + 1];
    __shared__ float act_s[COLS];

    const int wgid = blockIdx.x;
    const int b = wgid >> 3;        // batch (batch-contiguous)
    const int w = wgid & 7;         // WG-within-batch
    const int tid = threadIdx.x;
    const int c = tid & (COLS - 1); // col within WG: 0..127
    const int seg = tid >> 7;       // 0..3
    const int kbase = seg << 6;     // 0,64,128,192
    const int gg = c >> 5, jj = c & 31;
    const int colg = (gg << 8) + (w << 5) + jj;   // global preact column

    // one-time: my 64 U weights straight to registers
    float ureg[KLEN];
#pragma unroll
    for (int kk = 0; kk < KLEN; ++kk)
        ureg[kk] = U[(size_t)(kbase + kk) * FOUR_D + colg];

    float c_reg = 0.0f;
    if (tid < DPW) c_reg = cstate[b * DH + (w << 5) + tid];

    for (int tt = 0; tt < ct; ++tt) {
        const int s = t0 + tt + 1;     // computing h_s from h_{s-1}

        // px prefetch (independent of h): issue before the spin
        float pxv = 0.0f;
        if (tid < COLS)
            pxv = px[((size_t)tt * B_SZ + b) * FOUR_D + colg];

        // acquire h_{s-1}: threads 0..255 poll their own dim (tag==step)
        if (tid < DH) {
            if (s == 1) {
                h_lds[tid] = 0.0f;
            } else {
                const unsigned long long want = (unsigned long long)(unsigned)(s - 1);
                const unsigned long long* slot = hbuf +
                    (((size_t)((s - 1) & 1) * B_SZ + b) * DH + tid);
                unsigned long long v;
                do {
                    v = __hip_atomic_load(slot, __ATOMIC_RELAXED,
                                          __HIP_MEMORY_SCOPE_AGENT);
                } while ((v >> 32) != want);
                h_lds[tid] = __uint_as_float((unsigned)(v & 0xffffffffu));
            }
        }
        __syncthreads();   // B1: h_lds ready

        // GEMV: 64 fp32 FMAs per thread, U in regs, h broadcast from LDS
        float partial = 0.0f;
#pragma unroll
        for (int i = 0; i < KLEN; i += 4) {
            float4 h4 = *(const float4*)&h_lds[kbase + i];
            partial += h4.x * ureg[i]     + h4.y * ureg[i + 1]
                     + h4.z * ureg[i + 2] + h4.w * ureg[i + 3];
        }
        red[seg][c] = partial;
        __syncthreads();   // B2: partials ready

        if (tid < COLS) {
            float pre = pxv + red[0][tid] + red[1][tid]
                            + red[2][tid] + red[3][tid];
            // 128-wide activations: one transcendental round
            float a;
            if (tid < 96) {
                a = 1.0f / (1.0f + __expf(-pre));          // i, f, o
            } else {
                float e = __expf(-2.0f * pre);             // g = tanh
                a = 2.0f / (1.0f + e) - 1.0f;
            }
            act_s[tid] = a;
        }
        __syncthreads();   // B3: activations ready

        if (tid < DPW) {
            float ig = act_s[tid];
            float fg = act_s[32 + tid];
            float og = act_s[64 + tid];
            float gv = act_s[96 + tid];
            float cn = fg * c_reg + ig * gv;
            c_reg = cn;
            float ec = __expf(-2.0f * cn);
            float hn = og * (2.0f / (1.0f + ec) - 1.0f);
            const int d = (w << 5) + tid;
            // publish FIRST (critical path), out-store after
            unsigned long long pv =
                ((unsigned long long)(unsigned)s << 32) |
                (unsigned long long)__float_as_uint(hn);
            __hip_atomic_store(hbuf + (((size_t)(s & 1) * B_SZ + b) * DH + d),
                               pv, __ATOMIC_RELAXED, __HIP_MEMORY_SCOPE_AGENT);
            out[((size_t)b * T_SZ + (size_t)(s - 1)) * DH + d] = hn;
        }
        // no trailing barrier: pre-B1 writes next iter touch only h_lds,
        // whose readers all finished before B2 this iter.
    }

    if (tid < DPW) cstate[b * DH + (w << 5) + tid] = c_reg;
}

extern "C" void kernel_launch(void* const* d_in, const int* in_sizes, int n_in,
                              void* d_out, int out_size, void* d_ws, size_t ws_size,
                              hipStream_t stream) {
    const float* x    = (const float*)d_in[0];
    const float* W    = (const float*)d_in[1];
    const float* U    = (const float*)d_in[2];
    const float* bias = (const float*)d_in[3];
    float* out = (float*)d_out;

    // ws layout: cstate 32KB @0 | hbuf 128KB @32K | pxbuf @160K
    float* cstate = (float*)d_ws;
    unsigned long long* hbuf = (unsigned long long*)((char*)d_ws + 32 * 1024);
    size_t px_off = 160 * 1024;
    float* pxbuf = (float*)((char*)d_ws + px_off);

    size_t avail = (ws_size > px_off) ? (ws_size - px_off) : 0;
    size_t per_step = (size_t)B_SZ * FOUR_D * sizeof(float);  // 128 KB
    long ct_max = (long)(avail / per_step);
    int CT = (ct_max >= T_SZ) ? T_SZ : (int)ct_max;
    if (CT < 1) CT = 1;

    // zero cstate + hbuf each launch
    int zero_words = (160 * 1024) / 4;
    zero_ws<<<(zero_words + 255) / 256, 256, 0, stream>>>((unsigned int*)d_ws, zero_words);

    for (int t0 = 0; t0 < T_SZ; t0 += CT) {
        int ct = (T_SZ - t0 < CT) ? (T_SZ - t0) : CT;
        int rows = ct * B_SZ;
        px_gemm<<<rows / 16, 256, 0, stream>>>(x, W, bias, pxbuf, t0);
        lstm_scan5<<<B_SZ * NW, 512, 0, stream>>>(pxbuf, U, out, hbuf, cstate, t0, ct);
    }
}